// Round 3
// baseline (1707.356 us; speedup 1.0000x reference)
//
#include <hip/hip_runtime.h>
#include <hip/hip_bf16.h>
#include <stdint.h>

#define B_ 2
#define S_ 2048
#define D_ 4096
#define H_ 32
#define HD_ 128
#define HALF_ 64
#define AL_ 10
#define MROWS (B_*S_)   // 4096 rows of x / attn_out

typedef __hip_bfloat16 bf16;
typedef __attribute__((ext_vector_type(8))) __bf16 bf16x8;
typedef __attribute__((ext_vector_type(4))) float f32x4;
typedef __attribute__((ext_vector_type(4))) unsigned short us4;

// async global->LDS, 16B per lane. LDS dest = wave-uniform base + lane*16.
__device__ __forceinline__ void gld_lds16(const void* g, void* l) {
    __builtin_amdgcn_global_load_lds((const __attribute__((address_space(1))) void*)g,
                                     (__attribute__((address_space(3))) void*)l, 16, 0, 0);
}

// ---------------------------------------------------------------------------
// Input dtype detection. flag=1 -> fp32 inputs, flag=0 -> already bf16.
// ---------------------------------------------------------------------------
__global__ void detect_dtype(const unsigned short* __restrict__ x, int* __restrict__ flag) {
    __shared__ int cnt;
    if (threadIdx.x == 0) cnt = 0;
    __syncthreads();
    int bad = 0;
#pragma unroll
    for (int i = 0; i < 16; i++) {
        unsigned int u = x[threadIdx.x * 16 + i];
        float v = __uint_as_float(u << 16);
        if (!(fabsf(v) < 1000.f)) bad++;   // also true for NaN/Inf
    }
    atomicAdd(&cnt, bad);
    __syncthreads();
    if (threadIdx.x == 0) flag[0] = (cnt > 64) ? 1 : 0;
}

// Convert input (fp32 or bf16 per flag) to canonical bf16. n % 4 == 0.
__global__ void convert_bf16(const void* __restrict__ in, bf16* __restrict__ out,
                             const int* __restrict__ flag, int n) {
    int i = (blockIdx.x * 256 + threadIdx.x) * 4;
    if (i >= n) return;
    if (flag[0]) {
        float4 f = *(const float4*)((const float*)in + i);
        out[i + 0] = __float2bfloat16(f.x);
        out[i + 1] = __float2bfloat16(f.y);
        out[i + 2] = __float2bfloat16(f.z);
        out[i + 3] = __float2bfloat16(f.w);
    } else {
        *(us4*)(out + i) = *(const us4*)((const unsigned short*)in + i);
    }
}

// ---------------------------------------------------------------------------
// GEMM: C = A (M x K, row-major) @ W^T (W is N x K, row-major), bf16 in, fp32 acc.
// MODE 0: RoPE + *oscale + store to (B,H,S,HD)   (Q and K projections)
// MODE 1: store transposed to (B,H,HD,S)  (V projection)
// MODE 2: store to d_out as fp32 or bf16 per flag (output projection)
// ---------------------------------------------------------------------------
template<int MODE>
__global__ __launch_bounds__(256) void gemm_bt(
    const bf16* __restrict__ A, const bf16* __restrict__ W,
    const bf16* __restrict__ cosb, const bf16* __restrict__ sinb,
    void* __restrict__ outv, const int* __restrict__ flag, int K, float oscale)
{
    __shared__ __align__(16) bf16 sA[128*64];
    __shared__ __align__(16) bf16 sB[128*64];
    const int tid  = threadIdx.x;
    const int wave = tid >> 6, lane = tid & 63;
    const int quad = lane >> 4, col = lane & 15;
    const int m0 = blockIdx.y * 128, n0 = blockIdx.x * 128;
    const int wm = (wave >> 1) * 64, wn = (wave & 1) * 64;

    bool f32o = false;
    if (MODE == 2) f32o = (flag[0] != 0);

    f32x4 acc[4][4];
#pragma unroll
    for (int i = 0; i < 4; i++)
#pragma unroll
        for (int j = 0; j < 4; j++) acc[i][j] = {0.f, 0.f, 0.f, 0.f};

    for (int k0 = 0; k0 < K; k0 += 64) {
        __syncthreads();
#pragma unroll
        for (int i = 0; i < 4; i++) {
            int c   = i * 256 + tid;
            int row = c >> 3;
            int cc  = (c & 7) ^ (row & 7);
            gld_lds16(A + (size_t)(m0 + row) * K + k0 + cc * 8,
                      sA + (size_t)(i * 256 + wave * 64) * 8);
            gld_lds16(W + (size_t)(n0 + row) * K + k0 + cc * 8,
                      sB + (size_t)(i * 256 + wave * 64) * 8);
        }
        __syncthreads();

#pragma unroll
        for (int kk = 0; kk < 64; kk += 32) {
            bf16x8 af[4], bfr[4];
#pragma unroll
            for (int mt = 0; mt < 4; mt++) {
                int r  = wm + mt * 16 + col;
                int ck = ((kk >> 3) + quad) ^ (r & 7);
                af[mt] = *(const bf16x8*)(sA + r * 64 + ck * 8);
            }
#pragma unroll
            for (int nt = 0; nt < 4; nt++) {
                int r  = wn + nt * 16 + col;
                int ck = ((kk >> 3) + quad) ^ (r & 7);
                bfr[nt] = *(const bf16x8*)(sB + r * 64 + ck * 8);
            }
#pragma unroll
            for (int mt = 0; mt < 4; mt++)
#pragma unroll
                for (int nt = 0; nt < 4; nt++)
                    acc[mt][nt] = __builtin_amdgcn_mfma_f32_16x16x32_bf16(
                        af[mt], bfr[nt], acc[mt][nt], 0, 0, 0);
        }
    }

    // C/D layout: col = lane&15, row = quad*4 + e (verified m89/m91).
#pragma unroll
    for (int mt = 0; mt < 4; mt++) {
#pragma unroll
        for (int nt = 0; nt < 4; nt++) {
            int n = n0 + wn + nt * 16 + col;
#pragma unroll
            for (int e = 0; e < 4; e++) {
                int m   = m0 + wm + mt * 16 + quad * 4 + e;
                float v = acc[mt][nt][e];
                if (MODE == 2) {
                    if (f32o) ((float*)outv)[(size_t)m * D_ + n] = v;
                    else      ((bf16*)outv)[(size_t)m * D_ + n] = __float2bfloat16(v);
                } else {
                    int b = m >> 11, s = m & (S_ - 1);
                    int h = n >> 7,  hd = n & (HD_ - 1);
                    bf16* out = (bf16*)outv;
                    if (MODE == 0) {
                        float other = __shfl_xor(v, 1);
                        float c  = __bfloat162float(cosb[s * HALF_ + (hd >> 1)]);
                        float sn = __bfloat162float(sinb[s * HALF_ + (hd >> 1)]);
                        float r  = (hd & 1) ? (v * c + other * sn)
                                            : (v * c - other * sn);
                        out[((size_t)(b * H_ + h) * S_ + s) * HD_ + hd] =
                            __float2bfloat16(r * oscale);
                    } else { // MODE 1: V transposed -> (B,H,HD,S)
                        out[((size_t)(b * H_ + h) * HD_ + hd) * S_ + s] = __float2bfloat16(v);
                    }
                }
            }
        }
    }
}

// ---------------------------------------------------------------------------
// Flash attention, causal. Block = (b,h, 128-query tile), 256 thr = 4 waves.
// Wave w owns query rows [w*32, w*32+32) as two 16-row MFMA subtiles (rq=0,1)
// -> each K/V ds_read feeds 2 MFMAs. 256 thr (not 512) so __launch_bounds__
// caps VGPR at 256 -- the 512-thread variant pinned at 128 VGPR and spilled
// (R2: WRITE_SIZE 71MB vs 33MB output). Q pre-scaled by 1/sqrt(HD) in the
// projection GEMM; Q A-frags in registers. K/V double-buffered, counted vmcnt
// + raw s_barrier (T3/T4): never drain to 0 in the main loop. Softmax:
// exp2+fma, defer-rescale THR=8 (T13).
// LDS: K0|K1|V0|V1 (64KB) + P 128x64 (16KB) = 80KB -> 2 blocks/CU, 8 waves/CU.
// q,k: (B,H,S,HD)  v: (B,H,HD,S)  out: (B,S,H,HD)
// ---------------------------------------------------------------------------
__global__ __launch_bounds__(256, 2) void attn_fwd(
    const bf16* __restrict__ q, const bf16* __restrict__ k,
    const bf16* __restrict__ vT, bf16* __restrict__ o)
{
    __shared__ __align__(16) bf16 smem[40960];   // 80 KB
    bf16* sP = smem + 32768;    // 128 rows x 64 keys (16 KB)

    const int tid  = threadIdx.x, wave = tid >> 6, lane = tid & 63;
    const int quad = lane >> 4, col = lane & 15;
    const int qt = (gridDim.x - 1) - blockIdx.x;   // reverse: heavy blocks first
    const int bh = blockIdx.y;
    const int q0 = qt * 128;
    const int row0 = q0 + wave * 32;               // this wave's first query row
    const int rmax = row0 + 31;
    const bf16* qb = q  + (size_t)bh * S_ * HD_;
    const bf16* kb = k  + (size_t)bh * S_ * HD_;
    const bf16* vb = vT + (size_t)bh * HD_ * S_;

    // ---- Q fragments straight from global (pre-scaled by 1/sqrt(d))
    bf16x8 qf[2][4];
#pragma unroll
    for (int rq = 0; rq < 2; rq++)
#pragma unroll
        for (int kkI = 0; kkI < 4; kkI++)
            qf[rq][kkI] = *(const bf16x8*)(qb + (size_t)(row0 + rq * 16 + col) * HD_
                                              + (kkI * 4 + quad) * 8);

    float mst[2][4], lst[2][4];
#pragma unroll
    for (int rq = 0; rq < 2; rq++)
#pragma unroll
        for (int e = 0; e < 4; e++) { mst[rq][e] = -1e30f; lst[rq][e] = 0.f; }
    f32x4 oacc[2][8];
#pragma unroll
    for (int rq = 0; rq < 2; rq++)
#pragma unroll
        for (int i = 0; i < 8; i++) oacc[rq][i] = {0.f, 0.f, 0.f, 0.f};

    // ---- prologue: stage key-tile 0 into buffer 0 (4 K + 4 V gld per thread)
#pragma unroll
    for (int i = 0; i < 4; i++) {
        int c = i * 256 + tid;
        int rowK = c >> 4, ccK = (c & 15) ^ (rowK & 7);
        gld_lds16(kb + (size_t)rowK * HD_ + ccK * 8,
                  smem + (size_t)(i * 256 + wave * 64) * 8);
        int rowV = c >> 3, ccV = (c & 7) ^ (rowV & 7);
        gld_lds16(vb + (size_t)rowV * S_ + ccV * 8,
                  smem + 16384 + (size_t)(i * 256 + wave * 64) * 8);
    }

    const float L2E = 1.44269504088896f;
    const int ktEnd = 2 * qt + 2;
    int cur = 0;

    for (int kt = 0; kt < ktEnd; kt++) {
        const int k0 = kt * 64;
        bf16* sKc = smem + cur * 8192;
        bf16* sVc = smem + 16384 + cur * 8192;

        if (kt + 1 < ktEnd) {
            const int kn = k0 + 64;
            bf16* sKn = smem + (cur ^ 1) * 8192;
            bf16* sVn = smem + 16384 + (cur ^ 1) * 8192;
#pragma unroll
            for (int i = 0; i < 4; i++) {
                int c = i * 256 + tid;
                int rowK = c >> 4, ccK = (c & 15) ^ (rowK & 7);
                gld_lds16(kb + (size_t)(kn + rowK) * HD_ + ccK * 8,
                          sKn + (size_t)(i * 256 + wave * 64) * 8);
                int rowV = c >> 3, ccV = (c & 7) ^ (rowV & 7);
                gld_lds16(vb + (size_t)rowV * S_ + kn + ccV * 8,
                          sVn + (size_t)(i * 256 + wave * 64) * 8);
            }
            // wait only the CURRENT tile's 8 loads; the 8 just issued stay in flight
            asm volatile("s_waitcnt vmcnt(8)" ::: "memory");
        } else {
            asm volatile("s_waitcnt vmcnt(0)" ::: "memory");
        }
        asm volatile("s_barrier" ::: "memory");   // tile kt resident in LDS

        if (k0 <= rmax) {   // skip tiles entirely above this wave's diagonal
            // ---- S = Q K^T : 32 rows x 64 keys (each K-read feeds 2 MFMAs)
            f32x4 sc[2][4];
#pragma unroll
            for (int rq = 0; rq < 2; rq++)
#pragma unroll
                for (int nt = 0; nt < 4; nt++) sc[rq][nt] = {0.f, 0.f, 0.f, 0.f};
            __builtin_amdgcn_s_setprio(1);
#pragma unroll
            for (int kkI = 0; kkI < 4; kkI++) {
#pragma unroll
                for (int nt = 0; nt < 4; nt++) {
                    int rk  = nt * 16 + col;
                    int ckk = (kkI * 4 + quad) ^ (rk & 7);
                    bf16x8 bk = *(const bf16x8*)(sKc + rk * 128 + ckk * 8);
                    sc[0][nt] = __builtin_amdgcn_mfma_f32_16x16x32_bf16(qf[0][kkI], bk, sc[0][nt], 0, 0, 0);
                    sc[1][nt] = __builtin_amdgcn_mfma_f32_16x16x32_bf16(qf[1][kkI], bk, sc[1][nt], 0, 0, 0);
                }
            }
            __builtin_amdgcn_s_setprio(0);

            // ---- causal mask (scores already scaled; only last tiles hit diag)
#pragma unroll
            for (int rq = 0; rq < 2; rq++) {
                if (k0 + 63 > row0 + rq * 16) {
#pragma unroll
                    for (int nt = 0; nt < 4; nt++)
#pragma unroll
                        for (int e = 0; e < 4; e++)
                            if (k0 + nt * 16 + col > row0 + rq * 16 + quad * 4 + e)
                                sc[rq][nt][e] = -1e30f;
                }
            }

            // ---- row maxima (per-row state replicated across the quad's 16 lanes)
            float mxv[2][4];
#pragma unroll
            for (int rq = 0; rq < 2; rq++)
#pragma unroll
                for (int e = 0; e < 4; e++) {
                    float mx = fmaxf(fmaxf(sc[rq][0][e], sc[rq][1][e]),
                                     fmaxf(sc[rq][2][e], sc[rq][3][e]));
#pragma unroll
                    for (int off = 1; off < 16; off <<= 1) mx = fmaxf(mx, __shfl_xor(mx, off));
                    mxv[rq][e] = mx;
                }
            float need = -1e30f;
#pragma unroll
            for (int rq = 0; rq < 2; rq++)
#pragma unroll
                for (int e = 0; e < 4; e++) need = fmaxf(need, mxv[rq][e] - mst[rq][e]);

            if (__all(need <= 8.f)) {
                // ---- fast path (T13): keep old max, no rescale. P <= e^8.
#pragma unroll
                for (int rq = 0; rq < 2; rq++)
#pragma unroll
                    for (int e = 0; e < 4; e++) {
                        float nm = -mst[rq][e] * L2E;
                        float rs = 0.f;
                        int prow = wave * 32 + rq * 16 + quad * 4 + e;
                        int swz  = (prow & 7) ^ (((prow >> 3) & 1) << 1);
#pragma unroll
                        for (int nt = 0; nt < 4; nt++) {
                            float p = __builtin_amdgcn_exp2f(fmaf(sc[rq][nt][e], L2E, nm));
                            rs += p;
                            int pcol = nt * 16 + col;
                            int pc   = (pcol >> 3) ^ swz;
                            sP[prow * 64 + pc * 8 + (pcol & 7)] = __float2bfloat16(p);
                        }
#pragma unroll
                        for (int off = 1; off < 16; off <<= 1) rs += __shfl_xor(rs, off);
                        lst[rq][e] += rs;
                    }
            } else {
                float alpha_[2][4];
#pragma unroll
                for (int rq = 0; rq < 2; rq++)
#pragma unroll
                    for (int e = 0; e < 4; e++) {
                        float mnew = fmaxf(mst[rq][e], mxv[rq][e]);
                        float al   = __builtin_amdgcn_exp2f((mst[rq][e] - mnew) * L2E);
                        float nm   = -mnew * L2E;
                        float rs   = 0.f;
                        int prow = wave * 32 + rq * 16 + quad * 4 + e;
                        int swz  = (prow & 7) ^ (((prow >> 3) & 1) << 1);
#pragma unroll
                        for (int nt = 0; nt < 4; nt++) {
                            float p = __builtin_amdgcn_exp2f(fmaf(sc[rq][nt][e], L2E, nm));
                            rs += p;
                            int pcol = nt * 16 + col;
                            int pc   = (pcol >> 3) ^ swz;
                            sP[prow * 64 + pc * 8 + (pcol & 7)] = __float2bfloat16(p);
                        }
#pragma unroll
                        for (int off = 1; off < 16; off <<= 1) rs += __shfl_xor(rs, off);
                        lst[rq][e] = lst[rq][e] * al + rs;
                        mst[rq][e] = mnew;
                        alpha_[rq][e] = al;
                    }
#pragma unroll
                for (int rq = 0; rq < 2; rq++)
#pragma unroll
                    for (int nt = 0; nt < 8; nt++)
#pragma unroll
                        for (int e = 0; e < 4; e++) oacc[rq][nt][e] *= alpha_[rq][e];
            }

            // ---- O += P @ V. sP rows [wave*32, wave*32+32) are wave-private:
            // lgkmcnt ordering suffices, no barrier before PV.
            __builtin_amdgcn_s_setprio(1);
#pragma unroll
            for (int kkI = 0; kkI < 2; kkI++) {
                bf16x8 pf[2];
#pragma unroll
                for (int rq = 0; rq < 2; rq++) {
                    int rp  = wave * 32 + rq * 16 + col;
                    int ckp = (kkI * 4 + quad) ^ (rp & 7) ^ (((rp >> 3) & 1) << 1);
                    pf[rq] = *(const bf16x8*)(sP + rp * 64 + ckp * 8);
                }
#pragma unroll
                for (int nt = 0; nt < 8; nt++) {
                    int rv  = nt * 16 + col;
                    int ckv = (kkI * 4 + quad) ^ (rv & 7);
                    bf16x8 vf = *(const bf16x8*)(sVc + rv * 64 + ckv * 8);
                    oacc[0][nt] = __builtin_amdgcn_mfma_f32_16x16x32_bf16(pf[0], vf, oacc[0][nt], 0, 0, 0);
                    oacc[1][nt] = __builtin_amdgcn_mfma_f32_16x16x32_bf16(pf[1], vf, oacc[1][nt], 0, 0, 0);
                }
            }
            __builtin_amdgcn_s_setprio(0);
        }

        asm volatile("s_barrier" ::: "memory");   // all waves done reading buf[cur]
        cur ^= 1;
    }

    const int b = bh >> 5, h = bh & (H_ - 1);
#pragma unroll
    for (int rq = 0; rq < 2; rq++)
#pragma unroll
        for (int e = 0; e < 4; e++) {
            int s = q0 + wave * 32 + rq * 16 + quad * 4 + e;
            float inv = 1.f / lst[rq][e];
#pragma unroll
            for (int nt = 0; nt < 8; nt++) {
                int hd = nt * 16 + col;
                o[((size_t)(b * S_ + s) * H_ + h) * HD_ + hd] =
                    __float2bfloat16(oacc[rq][nt][e] * inv);
            }
        }
}

// ---------------------------------------------------------------------------
// a_k / a_v = adapter (B,AL,D) @ w^T. One wave per (b, n); blockIdx.y picks w.
// ---------------------------------------------------------------------------
__global__ __launch_bounds__(256) void adapter_kv(
    const bf16* __restrict__ adp, const bf16* __restrict__ wk,
    const bf16* __restrict__ wv, float* __restrict__ ak, float* __restrict__ av)
{
    const int tid = threadIdx.x, wave = tid >> 6, lane = tid & 63;
    const int gid = blockIdx.x * 4 + wave;
    const int n = gid & (D_ - 1), b = gid >> 12;
    const bf16* w    = blockIdx.y ? wv : wk;
    float*      outp = blockIdx.y ? av : ak;

    float acc[AL_];
#pragma unroll
    for (int j = 0; j < AL_; j++) acc[j] = 0.f;

    for (int t = 0; t < 8; t++) {
        int kb = t * 512 + lane * 8;
        bf16x8 w8 = *(const bf16x8*)(w + (size_t)n * D_ + kb);
        float wf[8];
#pragma unroll
        for (int i = 0; i < 8; i++) wf[i] = (float)w8[i];
#pragma unroll
        for (int j = 0; j < AL_; j++) {
            bf16x8 a8 = *(const bf16x8*)(adp + (size_t)(b * AL_ + j) * D_ + kb);
            float s = 0.f;
#pragma unroll
            for (int i = 0; i < 8; i++) s += (float)a8[i] * wf[i];
            acc[j] += s;
        }
    }
#pragma unroll
    for (int j = 0; j < AL_; j++) {
        float v = acc[j];
#pragma unroll
        for (int off = 1; off < 64; off <<= 1) v += __shfl_xor(v, off);
        if (lane == 0) outp[(size_t)(b * AL_ + j) * D_ + n] = v;
    }
}

// ---------------------------------------------------------------------------
// out += tanh(gate_h) * softmax(q . a_k^T) @ a_v.  One wave per query.
// (q is pre-scaled by 1/sqrt(d) in the projection GEMM -> no scale here.)
// ---------------------------------------------------------------------------
__global__ __launch_bounds__(256) void adapter_add(
    const bf16* __restrict__ q, const float* __restrict__ ak,
    const float* __restrict__ av, const bf16* __restrict__ gate,
    bf16* __restrict__ o)
{
    const int tid = threadIdx.x, wave = tid >> 6, lane = tid & 63;
    const int g = blockIdx.x * 4 + wave;
    const int s = g & (S_ - 1);
    const int h = (g >> 11) & (H_ - 1);
    const int b = g >> 16;
    const int hd = lane * 2;

    const bf16* qp = q + ((size_t)(b * H_ + h) * S_ + s) * HD_ + hd;
    float q0f = __bfloat162float(qp[0]);
    float q1f = __bfloat162float(qp[1]);

    float sc[AL_];
#pragma unroll
    for (int j = 0; j < AL_; j++) {
        const float* akp = ak + (size_t)(b * AL_ + j) * D_ + h * HD_ + hd;
        float p = q0f * akp[0] + q1f * akp[1];
#pragma unroll
        for (int off = 1; off < 64; off <<= 1) p += __shfl_xor(p, off);
        sc[j] = p;
    }
    float mx = sc[0];
#pragma unroll
    for (int j = 1; j < AL_; j++) mx = fmaxf(mx, sc[j]);
    float sum = 0.f;
#pragma unroll
    for (int j = 0; j < AL_; j++) { sc[j] = __expf(sc[j] - mx); sum += sc[j]; }
    float wgt = tanhf(__bfloat162float(gate[h])) / sum;

    float a0 = 0.f, a1 = 0.f;
#pragma unroll
    for (int j = 0; j < AL_; j++) {
        const float* avp = av + (size_t)(b * AL_ + j) * D_ + h * HD_ + hd;
        a0 += sc[j] * avp[0];
        a1 += sc[j] * avp[1];
    }
    bf16* op = o + ((size_t)(b * S_ + s) * H_ + h) * HD_ + hd;
    op[0] = __float2bfloat16(__bfloat162float(op[0]) + wgt * a0);
    op[1] = __float2bfloat16(__bfloat162float(op[1]) + wgt * a1);
}

// ---------------------------------------------------------------------------
extern "C" void kernel_launch(void* const* d_in, const int* in_sizes, int n_in,
                              void* d_out, int out_size, void* d_ws, size_t ws_size,
                              hipStream_t stream)
{
    const void* x_raw    = d_in[0];
    const void* cos_raw  = d_in[2];
    const void* sin_raw  = d_in[3];
    const void* wq_raw   = d_in[4];
    const void* wk_raw   = d_in[5];
    const void* wv_raw   = d_in[6];
    const void* wo_raw   = d_in[7];
    const void* gate_raw = d_in[8];
    const void* adp_raw  = d_in[9];

    const size_t NE = (size_t)B_ * S_ * D_;     // 16777216
    const int    CS = S_ * HALF_;               // 131072
    const int    AD = B_ * AL_ * D_;            // 81920

    bf16* xc   = (bf16*)d_ws;            // NE   (later reused as ab)
    bf16* wqc  = xc  + NE;               // NE
    bf16* wkc  = wqc + NE;               // NE
    bf16* wvc  = wkc + NE;               // NE
    bf16* woc  = wvc + NE;               // NE
    bf16* qb   = woc + NE;               // NE (roped+scaled Q, B,H,S,HD)
    bf16* kb   = qb  + NE;               // NE (roped K,  B,H,S,HD)
    bf16* vb   = kb  + NE;               // NE (V^T,      B,H,HD,S)
    bf16* cosc = vb  + NE;               // CS
    bf16* sinc = cosc + CS;              // CS
    bf16* adpc = sinc + CS;              // AD
    bf16* gatec= adpc + AD;              // 32
    float* akb = (float*)(gatec + 32);   // AD fp32
    float* avb = akb + AD;               // AD fp32
    int*  flag = (int*)(avb + AD);       // 1
    bf16* ab   = xc;                     // attention out (B,S,H,HD), aliases xc

    const float scale = 0.08838834764831845f;   // 1/sqrt(HD)

    dim3 blk(256);
    detect_dtype<<<1, 256, 0, stream>>>((const unsigned short*)x_raw, flag);

    convert_bf16<<<dim3((int)(NE/4 + 255) / 256), blk, 0, stream>>>(x_raw,  xc,  flag, (int)NE);
    convert_bf16<<<dim3((int)(NE/4 + 255) / 256), blk, 0, stream>>>(wq_raw, wqc, flag, (int)NE);
    convert_bf16<<<dim3((int)(NE/4 + 255) / 256), blk, 0, stream>>>(wk_raw, wkc, flag, (int)NE);
    convert_bf16<<<dim3((int)(NE/4 + 255) / 256), blk, 0, stream>>>(wv_raw, wvc, flag, (int)NE);
    convert_bf16<<<dim3((int)(NE/4 + 255) / 256), blk, 0, stream>>>(wo_raw, woc, flag, (int)NE);
    convert_bf16<<<dim3((CS/4 + 255) / 256), blk, 0, stream>>>(cos_raw,  cosc, flag, CS);
    convert_bf16<<<dim3((CS/4 + 255) / 256), blk, 0, stream>>>(sin_raw,  sinc, flag, CS);
    convert_bf16<<<dim3((AD/4 + 255) / 256), blk, 0, stream>>>(adp_raw,  adpc, flag, AD);
    convert_bf16<<<dim3(1), blk, 0, stream>>>(gate_raw, gatec, flag, 32);

    dim3 gg(D_ / 128, MROWS / 128);
    gemm_bt<0><<<gg, blk, 0, stream>>>(xc, wqc, cosc, sinc, qb, flag, D_, scale);
    gemm_bt<0><<<gg, blk, 0, stream>>>(xc, wkc, cosc, sinc, kb, flag, D_, 1.0f);
    gemm_bt<1><<<gg, blk, 0, stream>>>(xc, wvc, cosc, sinc, vb, flag, D_, 1.0f);
    adapter_kv<<<dim3(2048, 2), blk, 0, stream>>>(adpc, wkc, wvc, akb, avb);
    attn_fwd<<<dim3(S_ / 128, B_ * H_), dim3(256), 0, stream>>>(qb, kb, vb, ab);
    adapter_add<<<dim3(B_ * H_ * S_ / 4), blk, 0, stream>>>(qb, akb, avb, gatec, ab);
    gemm_bt<2><<<gg, blk, 0, stream>>>(ab, woc, cosc, sinc, d_out, flag, D_, 1.0f);
}

// Round 4
// 1337.981 us; speedup vs baseline: 1.2761x; 1.2761x over previous
//
#include <hip/hip_runtime.h>
#include <hip/hip_bf16.h>
#include <stdint.h>

#define B_ 2
#define S_ 2048
#define D_ 4096
#define H_ 32
#define HD_ 128
#define HALF_ 64
#define AL_ 10
#define MROWS (B_*S_)   // 4096 rows of x / attn_out
#define NQT_ (S_/128)   // 16 query tiles of 128 rows

typedef __hip_bfloat16 bf16;
typedef __attribute__((ext_vector_type(8))) __bf16 bf16x8;
typedef __attribute__((ext_vector_type(4))) float f32x4;
typedef __attribute__((ext_vector_type(4))) unsigned short us4;

// async global->LDS, 16B per lane. LDS dest = wave-uniform base + lane*16.
__device__ __forceinline__ void gld_lds16(const void* g, void* l) {
    __builtin_amdgcn_global_load_lds((const __attribute__((address_space(1))) void*)g,
                                     (__attribute__((address_space(3))) void*)l, 16, 0, 0);
}

// ---------------------------------------------------------------------------
// Input dtype detection. flag=1 -> fp32 inputs, flag=0 -> already bf16.
// ---------------------------------------------------------------------------
__global__ void detect_dtype(const unsigned short* __restrict__ x, int* __restrict__ flag) {
    __shared__ int cnt;
    if (threadIdx.x == 0) cnt = 0;
    __syncthreads();
    int bad = 0;
#pragma unroll
    for (int i = 0; i < 16; i++) {
        unsigned int u = x[threadIdx.x * 16 + i];
        float v = __uint_as_float(u << 16);
        if (!(fabsf(v) < 1000.f)) bad++;   // also true for NaN/Inf
    }
    atomicAdd(&cnt, bad);
    __syncthreads();
    if (threadIdx.x == 0) flag[0] = (cnt > 64) ? 1 : 0;
}

// Convert input (fp32 or bf16 per flag) to canonical bf16. n % 4 == 0.
__global__ void convert_bf16(const void* __restrict__ in, bf16* __restrict__ out,
                             const int* __restrict__ flag, int n) {
    int i = (blockIdx.x * 256 + threadIdx.x) * 4;
    if (i >= n) return;
    if (flag[0]) {
        float4 f = *(const float4*)((const float*)in + i);
        out[i + 0] = __float2bfloat16(f.x);
        out[i + 1] = __float2bfloat16(f.y);
        out[i + 2] = __float2bfloat16(f.z);
        out[i + 3] = __float2bfloat16(f.w);
    } else {
        *(us4*)(out + i) = *(const us4*)((const unsigned short*)in + i);
    }
}

// ---------------------------------------------------------------------------
// GEMM: C = A (M x K, row-major) @ W^T (W is N x K, row-major), bf16 in, fp32 acc.
// MODE 0: RoPE + *oscale + store to (B,H,S,HD)   (Q and K projections)
// MODE 1: store transposed to (B,H,HD,S)  (V projection)
// MODE 2: store to d_out as fp32 or bf16 per flag (output projection)
// ---------------------------------------------------------------------------
template<int MODE>
__global__ __launch_bounds__(256) void gemm_bt(
    const bf16* __restrict__ A, const bf16* __restrict__ W,
    const bf16* __restrict__ cosb, const bf16* __restrict__ sinb,
    void* __restrict__ outv, const int* __restrict__ flag, int K, float oscale)
{
    __shared__ __align__(16) bf16 sA[128*64];
    __shared__ __align__(16) bf16 sB[128*64];
    const int tid  = threadIdx.x;
    const int wave = tid >> 6, lane = tid & 63;
    const int quad = lane >> 4, col = lane & 15;
    const int m0 = blockIdx.y * 128, n0 = blockIdx.x * 128;
    const int wm = (wave >> 1) * 64, wn = (wave & 1) * 64;

    bool f32o = false;
    if (MODE == 2) f32o = (flag[0] != 0);

    f32x4 acc[4][4];
#pragma unroll
    for (int i = 0; i < 4; i++)
#pragma unroll
        for (int j = 0; j < 4; j++) acc[i][j] = {0.f, 0.f, 0.f, 0.f};

    for (int k0 = 0; k0 < K; k0 += 64) {
        __syncthreads();
#pragma unroll
        for (int i = 0; i < 4; i++) {
            int c   = i * 256 + tid;
            int row = c >> 3;
            int cc  = (c & 7) ^ (row & 7);
            gld_lds16(A + (size_t)(m0 + row) * K + k0 + cc * 8,
                      sA + (size_t)(i * 256 + wave * 64) * 8);
            gld_lds16(W + (size_t)(n0 + row) * K + k0 + cc * 8,
                      sB + (size_t)(i * 256 + wave * 64) * 8);
        }
        __syncthreads();

#pragma unroll
        for (int kk = 0; kk < 64; kk += 32) {
            bf16x8 af[4], bfr[4];
#pragma unroll
            for (int mt = 0; mt < 4; mt++) {
                int r  = wm + mt * 16 + col;
                int ck = ((kk >> 3) + quad) ^ (r & 7);
                af[mt] = *(const bf16x8*)(sA + r * 64 + ck * 8);
            }
#pragma unroll
            for (int nt = 0; nt < 4; nt++) {
                int r  = wn + nt * 16 + col;
                int ck = ((kk >> 3) + quad) ^ (r & 7);
                bfr[nt] = *(const bf16x8*)(sB + r * 64 + ck * 8);
            }
#pragma unroll
            for (int mt = 0; mt < 4; mt++)
#pragma unroll
                for (int nt = 0; nt < 4; nt++)
                    acc[mt][nt] = __builtin_amdgcn_mfma_f32_16x16x32_bf16(
                        af[mt], bfr[nt], acc[mt][nt], 0, 0, 0);
        }
    }

    // C/D layout: col = lane&15, row = quad*4 + e (verified m89/m91).
#pragma unroll
    for (int mt = 0; mt < 4; mt++) {
#pragma unroll
        for (int nt = 0; nt < 4; nt++) {
            int n = n0 + wn + nt * 16 + col;
#pragma unroll
            for (int e = 0; e < 4; e++) {
                int m   = m0 + wm + mt * 16 + quad * 4 + e;
                float v = acc[mt][nt][e];
                if (MODE == 2) {
                    if (f32o) ((float*)outv)[(size_t)m * D_ + n] = v;
                    else      ((bf16*)outv)[(size_t)m * D_ + n] = __float2bfloat16(v);
                } else {
                    int b = m >> 11, s = m & (S_ - 1);
                    int h = n >> 7,  hd = n & (HD_ - 1);
                    bf16* out = (bf16*)outv;
                    if (MODE == 0) {
                        float other = __shfl_xor(v, 1);
                        float c  = __bfloat162float(cosb[s * HALF_ + (hd >> 1)]);
                        float sn = __bfloat162float(sinb[s * HALF_ + (hd >> 1)]);
                        float r  = (hd & 1) ? (v * c + other * sn)
                                            : (v * c - other * sn);
                        out[((size_t)(b * H_ + h) * S_ + s) * HD_ + hd] =
                            __float2bfloat16(r * oscale);
                    } else { // MODE 1: V transposed -> (B,H,HD,S)
                        out[((size_t)(b * H_ + h) * HD_ + hd) * S_ + s] = __float2bfloat16(v);
                    }
                }
            }
        }
    }
}

// ---------------------------------------------------------------------------
// Flash attention, causal. Block = (b,h, PAIR of 128-query tiles qt and
// 15-qt) -> every block does exactly 34 key-tile iterations (perfect balance,
// 512 blocks = 2/CU, one residency round). 512 thr = 8 waves; wave w owns 16
// query rows (one MFMA subtile) -- the 16-row/wave geometry is the verified
// no-spill point (R1: 64 VGPR; 32-row variants spill at the 128-reg
// allocator ceiling, R2/R3). Q pre-scaled by 1/sqrt(HD) in the projection
// GEMM; Q A-frags in registers. K/V double-buffered, counted vmcnt + raw
// s_barrier (T3/T4): never drain to 0 in the main loop. Softmax: exp2+fma,
// unified-body defer-rescale THR=8 (T13: rescale branch only touches
// m/l/oacc -- single exp/store loop, no code duplication -> no reg blowup).
// sP swizzle has the extra ((row>>3)&1)<<1 bit: quad0/quad2 write conflict
// (4-way) becomes conflict-free.
// LDS: K0|K1|V0|V1 (64KB) + P 128x64 (16KB) = 80KB -> 2 blocks/CU.
// q,k: (B,H,S,HD)  v: (B,H,HD,S)  out: (B,S,H,HD)
// ---------------------------------------------------------------------------
__global__ __launch_bounds__(512, 4) void attn_fwd(
    const bf16* __restrict__ q, const bf16* __restrict__ k,
    const bf16* __restrict__ vT, bf16* __restrict__ o)
{
    __shared__ __align__(16) bf16 smem[40960];   // 80 KB
    bf16* sP = smem + 32768;    // 128 rows x 64 keys (16 KB)

    const int tid  = threadIdx.x, wave = tid >> 6, lane = tid & 63;
    const int quad = lane >> 4, col = lane & 15;
    const int bh = blockIdx.y;
    const int b = bh >> 5, h = bh & (H_ - 1);
    const bf16* qb = q  + (size_t)bh * S_ * HD_;
    const bf16* kb = k  + (size_t)bh * S_ * HD_;
    const bf16* vb = vT + (size_t)bh * HD_ * S_;
    const float L2E = 1.44269504088896f;

#pragma unroll 1
    for (int pass = 0; pass < 2; pass++) {
        const int qt = pass ? (NQT_ - 1 - (int)blockIdx.x) : (int)blockIdx.x;
        const int q0 = qt * 128;
        const int row0 = q0 + wave * 16;           // this wave's first query row
        const int rmax = row0 + 15;

        // ---- Q fragments straight from global (pre-scaled by 1/sqrt(d))
        bf16x8 qf[4];
#pragma unroll
        for (int kkI = 0; kkI < 4; kkI++)
            qf[kkI] = *(const bf16x8*)(qb + (size_t)(row0 + col) * HD_
                                          + (kkI * 4 + quad) * 8);

        float mst[4], lst[4];
#pragma unroll
        for (int e = 0; e < 4; e++) { mst[e] = -1e30f; lst[e] = 0.f; }
        f32x4 oacc[8];
#pragma unroll
        for (int i = 0; i < 8; i++) oacc[i] = {0.f, 0.f, 0.f, 0.f};

        // ---- prologue: stage key-tile 0 into buffer 0 (2 K + 2 V gld/thread)
        // (safe even mid-kernel: previous pass's loop ends with s_barrier)
#pragma unroll
        for (int i = 0; i < 2; i++) {
            int c = i * 512 + tid;
            int rowK = c >> 4, ccK = (c & 15) ^ (rowK & 7);
            gld_lds16(kb + (size_t)rowK * HD_ + ccK * 8,
                      smem + (size_t)(i * 512 + wave * 64) * 8);
            int rowV = c >> 3, ccV = (c & 7) ^ (rowV & 7);
            gld_lds16(vb + (size_t)rowV * S_ + ccV * 8,
                      smem + 16384 + (size_t)(i * 512 + wave * 64) * 8);
        }

        const int ktEnd = 2 * qt + 2;
        int cur = 0;

        for (int kt = 0; kt < ktEnd; kt++) {
            const int k0 = kt * 64;
            bf16* sKc = smem + cur * 8192;
            bf16* sVc = smem + 16384 + cur * 8192;

            if (kt + 1 < ktEnd) {
                const int kn = k0 + 64;
                bf16* sKn = smem + (cur ^ 1) * 8192;
                bf16* sVn = smem + 16384 + (cur ^ 1) * 8192;
#pragma unroll
                for (int i = 0; i < 2; i++) {
                    int c = i * 512 + tid;
                    int rowK = c >> 4, ccK = (c & 15) ^ (rowK & 7);
                    gld_lds16(kb + (size_t)(kn + rowK) * HD_ + ccK * 8,
                              sKn + (size_t)(i * 512 + wave * 64) * 8);
                    int rowV = c >> 3, ccV = (c & 7) ^ (rowV & 7);
                    gld_lds16(vb + (size_t)rowV * S_ + kn + ccV * 8,
                              sVn + (size_t)(i * 512 + wave * 64) * 8);
                }
                // wait only the CURRENT tile's 4 loads; the 4 just issued stay in flight
                asm volatile("s_waitcnt vmcnt(4)" ::: "memory");
            } else {
                asm volatile("s_waitcnt vmcnt(0)" ::: "memory");
            }
            asm volatile("s_barrier" ::: "memory");   // tile kt resident in LDS

            if (k0 <= rmax) {   // skip tiles entirely above this wave's diagonal
                // ---- S = Q K^T : 16 rows x 64 keys for this wave
                f32x4 sc[4];
#pragma unroll
                for (int nt = 0; nt < 4; nt++) sc[nt] = {0.f, 0.f, 0.f, 0.f};
                __builtin_amdgcn_s_setprio(1);
#pragma unroll
                for (int kkI = 0; kkI < 4; kkI++) {
#pragma unroll
                    for (int nt = 0; nt < 4; nt++) {
                        int rk  = nt * 16 + col;
                        int ckk = (kkI * 4 + quad) ^ (rk & 7);
                        bf16x8 bk = *(const bf16x8*)(sKc + rk * 128 + ckk * 8);
                        sc[nt] = __builtin_amdgcn_mfma_f32_16x16x32_bf16(qf[kkI], bk, sc[nt], 0, 0, 0);
                    }
                }
                __builtin_amdgcn_s_setprio(0);

                // ---- causal mask (scores already scaled; only diag tiles)
                if (k0 + 63 > row0) {
#pragma unroll
                    for (int nt = 0; nt < 4; nt++)
#pragma unroll
                        for (int e = 0; e < 4; e++)
                            if (k0 + nt * 16 + col > row0 + quad * 4 + e)
                                sc[nt][e] = -1e30f;
                }

                // ---- row maxima (state replicated across the quad's 16 lanes)
                float mxv[4];
#pragma unroll
                for (int e = 0; e < 4; e++) {
                    float mx = fmaxf(fmaxf(sc[0][e], sc[1][e]),
                                     fmaxf(sc[2][e], sc[3][e]));
#pragma unroll
                    for (int off = 1; off < 16; off <<= 1) mx = fmaxf(mx, __shfl_xor(mx, off));
                    mxv[e] = mx;
                }
                float need = fmaxf(fmaxf(mxv[0] - mst[0], mxv[1] - mst[1]),
                                   fmaxf(mxv[2] - mst[2], mxv[3] - mst[3]));

                // T13: only rescale when the max actually grew past THR=8.
                if (!__all(need <= 8.f)) {
                    float alpha_[4];
#pragma unroll
                    for (int e = 0; e < 4; e++) {
                        float mnew = fmaxf(mst[e], mxv[e]);
                        float al   = __builtin_amdgcn_exp2f((mst[e] - mnew) * L2E);
                        mst[e] = mnew;
                        lst[e] *= al;
                        alpha_[e] = al;
                    }
#pragma unroll
                    for (int nt = 0; nt < 8; nt++)
#pragma unroll
                        for (int e = 0; e < 4; e++) oacc[nt][e] *= alpha_[e];
                }

                // ---- unified exp + P-store + row-sum (single body)
#pragma unroll
                for (int e = 0; e < 4; e++) {
                    float nm = -mst[e] * L2E;
                    float rs = 0.f;
                    int prow = wave * 16 + quad * 4 + e;
                    int fsw  = (prow & 7) ^ (((prow >> 3) & 1) << 1);
#pragma unroll
                    for (int nt = 0; nt < 4; nt++) {
                        float p = __builtin_amdgcn_exp2f(fmaf(sc[nt][e], L2E, nm));
                        rs += p;
                        int pcol = nt * 16 + col;
                        int pc   = (pcol >> 3) ^ fsw;
                        sP[prow * 64 + pc * 8 + (pcol & 7)] = __float2bfloat16(p);
                    }
#pragma unroll
                    for (int off = 1; off < 16; off <<= 1) rs += __shfl_xor(rs, off);
                    lst[e] += rs;
                }

                // ---- O += P @ V. sP rows [wave*16, wave*16+16) are wave-
                // private: lgkmcnt ordering suffices, no barrier before PV.
                __builtin_amdgcn_s_setprio(1);
#pragma unroll
                for (int kkI = 0; kkI < 2; kkI++) {
                    int rp  = wave * 16 + col;
                    int fsw = (rp & 7) ^ (((rp >> 3) & 1) << 1);
                    int ckp = (kkI * 4 + quad) ^ fsw;
                    bf16x8 pf = *(const bf16x8*)(sP + rp * 64 + ckp * 8);
#pragma unroll
                    for (int nt = 0; nt < 8; nt++) {
                        int rv  = nt * 16 + col;
                        int ckv = (kkI * 4 + quad) ^ (rv & 7);
                        bf16x8 vf = *(const bf16x8*)(sVc + rv * 64 + ckv * 8);
                        oacc[nt] = __builtin_amdgcn_mfma_f32_16x16x32_bf16(pf, vf, oacc[nt], 0, 0, 0);
                    }
                }
                __builtin_amdgcn_s_setprio(0);
            }

            asm volatile("s_barrier" ::: "memory");   // all waves done with buf[cur]
            cur ^= 1;
        }

        // ---- epilogue for this q-tile
#pragma unroll
        for (int e = 0; e < 4; e++) {
            int s = row0 + quad * 4 + e;
            float inv = 1.f / lst[e];
#pragma unroll
            for (int nt = 0; nt < 8; nt++) {
                int hd = nt * 16 + col;
                o[((size_t)(b * S_ + s) * H_ + h) * HD_ + hd] =
                    __float2bfloat16(oacc[nt][e] * inv);
            }
        }
    }
}

// ---------------------------------------------------------------------------
// a_k / a_v = adapter (B,AL,D) @ w^T. One wave per (b, n); blockIdx.y picks w.
// ---------------------------------------------------------------------------
__global__ __launch_bounds__(256) void adapter_kv(
    const bf16* __restrict__ adp, const bf16* __restrict__ wk,
    const bf16* __restrict__ wv, float* __restrict__ ak, float* __restrict__ av)
{
    const int tid = threadIdx.x, wave = tid >> 6, lane = tid & 63;
    const int gid = blockIdx.x * 4 + wave;
    const int n = gid & (D_ - 1), b = gid >> 12;
    const bf16* w    = blockIdx.y ? wv : wk;
    float*      outp = blockIdx.y ? av : ak;

    float acc[AL_];
#pragma unroll
    for (int j = 0; j < AL_; j++) acc[j] = 0.f;

    for (int t = 0; t < 8; t++) {
        int kb = t * 512 + lane * 8;
        bf16x8 w8 = *(const bf16x8*)(w + (size_t)n * D_ + kb);
        float wf[8];
#pragma unroll
        for (int i = 0; i < 8; i++) wf[i] = (float)w8[i];
#pragma unroll
        for (int j = 0; j < AL_; j++) {
            bf16x8 a8 = *(const bf16x8*)(adp + (size_t)(b * AL_ + j) * D_ + kb);
            float s = 0.f;
#pragma unroll
            for (int i = 0; i < 8; i++) s += (float)a8[i] * wf[i];
            acc[j] += s;
        }
    }
#pragma unroll
    for (int j = 0; j < AL_; j++) {
        float v = acc[j];
#pragma unroll
        for (int off = 1; off < 64; off <<= 1) v += __shfl_xor(v, off);
        if (lane == 0) outp[(size_t)(b * AL_ + j) * D_ + n] = v;
    }
}

// ---------------------------------------------------------------------------
// out += tanh(gate_h) * softmax(q . a_k^T) @ a_v.  One wave per query.
// (q is pre-scaled by 1/sqrt(d) in the projection GEMM -> no scale here.)
// ---------------------------------------------------------------------------
__global__ __launch_bounds__(256) void adapter_add(
    const bf16* __restrict__ q, const float* __restrict__ ak,
    const float* __restrict__ av, const bf16* __restrict__ gate,
    bf16* __restrict__ o)
{
    const int tid = threadIdx.x, wave = tid >> 6, lane = tid & 63;
    const int g = blockIdx.x * 4 + wave;
    const int s = g & (S_ - 1);
    const int h = (g >> 11) & (H_ - 1);
    const int b = g >> 16;
    const int hd = lane * 2;

    const bf16* qp = q + ((size_t)(b * H_ + h) * S_ + s) * HD_ + hd;
    float q0f = __bfloat162float(qp[0]);
    float q1f = __bfloat162float(qp[1]);

    float sc[AL_];
#pragma unroll
    for (int j = 0; j < AL_; j++) {
        const float* akp = ak + (size_t)(b * AL_ + j) * D_ + h * HD_ + hd;
        float p = q0f * akp[0] + q1f * akp[1];
#pragma unroll
        for (int off = 1; off < 64; off <<= 1) p += __shfl_xor(p, off);
        sc[j] = p;
    }
    float mx = sc[0];
#pragma unroll
    for (int j = 1; j < AL_; j++) mx = fmaxf(mx, sc[j]);
    float sum = 0.f;
#pragma unroll
    for (int j = 0; j < AL_; j++) { sc[j] = __expf(sc[j] - mx); sum += sc[j]; }
    float wgt = tanhf(__bfloat162float(gate[h])) / sum;

    float a0 = 0.f, a1 = 0.f;
#pragma unroll
    for (int j = 0; j < AL_; j++) {
        const float* avp = av + (size_t)(b * AL_ + j) * D_ + h * HD_ + hd;
        a0 += sc[j] * avp[0];
        a1 += sc[j] * avp[1];
    }
    bf16* op = o + ((size_t)(b * S_ + s) * H_ + h) * HD_ + hd;
    op[0] = __float2bfloat16(__bfloat162float(op[0]) + wgt * a0);
    op[1] = __float2bfloat16(__bfloat162float(op[1]) + wgt * a1);
}

// ---------------------------------------------------------------------------
extern "C" void kernel_launch(void* const* d_in, const int* in_sizes, int n_in,
                              void* d_out, int out_size, void* d_ws, size_t ws_size,
                              hipStream_t stream)
{
    const void* x_raw    = d_in[0];
    const void* cos_raw  = d_in[2];
    const void* sin_raw  = d_in[3];
    const void* wq_raw   = d_in[4];
    const void* wk_raw   = d_in[5];
    const void* wv_raw   = d_in[6];
    const void* wo_raw   = d_in[7];
    const void* gate_raw = d_in[8];
    const void* adp_raw  = d_in[9];

    const size_t NE = (size_t)B_ * S_ * D_;     // 16777216
    const int    CS = S_ * HALF_;               // 131072
    const int    AD = B_ * AL_ * D_;            // 81920

    bf16* xc   = (bf16*)d_ws;            // NE   (later reused as ab)
    bf16* wqc  = xc  + NE;               // NE
    bf16* wkc  = wqc + NE;               // NE
    bf16* wvc  = wkc + NE;               // NE
    bf16* woc  = wvc + NE;               // NE
    bf16* qb   = woc + NE;               // NE (roped+scaled Q, B,H,S,HD)
    bf16* kb   = qb  + NE;               // NE (roped K,  B,H,S,HD)
    bf16* vb   = kb  + NE;               // NE (V^T,      B,H,HD,S)
    bf16* cosc = vb  + NE;               // CS
    bf16* sinc = cosc + CS;              // CS
    bf16* adpc = sinc + CS;              // AD
    bf16* gatec= adpc + AD;              // 32
    float* akb = (float*)(gatec + 32);   // AD fp32
    float* avb = akb + AD;               // AD fp32
    int*  flag = (int*)(avb + AD);       // 1
    bf16* ab   = xc;                     // attention out (B,S,H,HD), aliases xc

    const float scale = 0.08838834764831845f;   // 1/sqrt(HD)

    dim3 blk(256);
    detect_dtype<<<1, 256, 0, stream>>>((const unsigned short*)x_raw, flag);

    convert_bf16<<<dim3((int)(NE/4 + 255) / 256), blk, 0, stream>>>(x_raw,  xc,  flag, (int)NE);
    convert_bf16<<<dim3((int)(NE/4 + 255) / 256), blk, 0, stream>>>(wq_raw, wqc, flag, (int)NE);
    convert_bf16<<<dim3((int)(NE/4 + 255) / 256), blk, 0, stream>>>(wk_raw, wkc, flag, (int)NE);
    convert_bf16<<<dim3((int)(NE/4 + 255) / 256), blk, 0, stream>>>(wv_raw, wvc, flag, (int)NE);
    convert_bf16<<<dim3((int)(NE/4 + 255) / 256), blk, 0, stream>>>(wo_raw, woc, flag, (int)NE);
    convert_bf16<<<dim3((CS/4 + 255) / 256), blk, 0, stream>>>(cos_raw,  cosc, flag, CS);
    convert_bf16<<<dim3((CS/4 + 255) / 256), blk, 0, stream>>>(sin_raw,  sinc, flag, CS);
    convert_bf16<<<dim3((AD/4 + 255) / 256), blk, 0, stream>>>(adp_raw,  adpc, flag, AD);
    convert_bf16<<<dim3(1), blk, 0, stream>>>(gate_raw, gatec, flag, 32);

    dim3 gg(D_ / 128, MROWS / 128);
    gemm_bt<0><<<gg, blk, 0, stream>>>(xc, wqc, cosc, sinc, qb, flag, D_, scale);
    gemm_bt<0><<<gg, blk, 0, stream>>>(xc, wkc, cosc, sinc, kb, flag, D_, 1.0f);
    gemm_bt<1><<<gg, blk, 0, stream>>>(xc, wvc, cosc, sinc, vb, flag, D_, 1.0f);
    adapter_kv<<<dim3(2048, 2), blk, 0, stream>>>(adpc, wkc, wvc, akb, avb);
    attn_fwd<<<dim3(NQT_ / 2, B_ * H_), dim3(512), 0, stream>>>(qb, kb, vb, ab);
    adapter_add<<<dim3(B_ * H_ * S_ / 4), blk, 0, stream>>>(qb, akb, avb, gatec, ab);
    gemm_bt<2><<<gg, blk, 0, stream>>>(ab, woc, cosc, sinc, d_out, flag, D_, 1.0f);
}